// Round 2
// baseline (681.112 us; speedup 1.0000x reference)
//
#include <hip/hip_runtime.h>
#include <cstdint>
#include <cstddef>
#include <math.h>

#define TOKENS 16384
#define DIM    4096
#define NE     64
#define MT     128          // tokens per block tile
#define KT     32           // k elements staged per step
#define KT4    (KT/4)       // float4 per row = 8
#define X_F4   (MT*KT4)     // 1024 float4 per x buffer (16 KB)
#define PART_ELEMS ((size_t)TOKENS * NE)

static_assert(TOKENS % MT == 0, "tile");

__device__ __forceinline__ int swz(int row) { return (row >> 2) & 7; }

__device__ __forceinline__ void gload16(const void* g, void* l) {
  __builtin_amdgcn_global_load_lds(
      (const __attribute__((address_space(1))) void*)g,
      (__attribute__((address_space(3))) void*)l, 16, 0, 0);
}

// GEMM: partial logits [token][expert] for one K-split.
// grid = 128 m-tiles * split, block = 256 (4 waves).
// X staged in LDS (double-buffered, 32 KB -> 4 blocks/CU); W read from L2.
__global__ __launch_bounds__(256, 4)
void dr_gemm(const float* __restrict__ x, const float* __restrict__ gw,
             float* __restrict__ p0, float* __restrict__ pws, int steps)
{
  __shared__ float4 xs4[2 * X_F4];

  const int t    = threadIdx.x;
  const int lane = t & 63;
  const int wv   = t >> 6;     // wave 0..3
  const int ng   = t & 15;     // expert-group thread (4 experts)
  const int mg   = t >> 4;     // token-group thread (8 tokens)

  const int bm    = blockIdx.x & 127;
  const int h     = blockIdx.x >> 7;            // K-split index
  const int kbase = h * steps * KT;
  float* __restrict__ dst = h ? (pws + (size_t)(h - 1) * PART_ELEMS) : p0;

  // --- X staging constants (global byte offsets exclude per-step k advance) ---
  size_t xoff[4]; int xlds[4];
#pragma unroll
  for (int r = 0; r < 4; ++r) {
    int row = r * 32 + wv * 8 + (lane >> 3);          // 0..127
    int c4  = (lane & 7) ^ swz(row);                  // pre-swizzled source column
    xoff[r] = ((size_t)(bm * MT + row) * DIM + kbase + 4 * c4) * sizeof(float);
    xlds[r] = (r * 32 + wv * 8) * KT4;                // wave-uniform LDS base (float4)
  }
  const char* xb = (const char*)x;

  auto stage = [&](int buf, int sidx) {
    size_t kb = (size_t)sidx * KT * sizeof(float);
#pragma unroll
    for (int r = 0; r < 4; ++r)
      gload16(xb + xoff[r] + kb, (void*)(xs4 + buf * X_F4 + xlds[r]));
  };

  // W direct from global (L2-resident: 1 MB total). Per-thread base: expert 4*ng.
  const float4* __restrict__ w4 = reinterpret_cast<const float4*>(gw)
                                  + (size_t)(4 * ng) * (DIM / 4) + (kbase >> 2);

  float acc[8][4];
#pragma unroll
  for (int i = 0; i < 8; ++i)
#pragma unroll
    for (int j = 0; j < 4; ++j) acc[i][j] = 0.f;

  stage(0, 0);
  __syncthreads();

  int buf = 0;
#pragma unroll 1
  for (int s = 0; s < steps; ++s) {
    if (s + 1 < steps) stage(buf ^ 1, s + 1);   // async prefetch, drained at barrier
    const float4* X  = xs4 + buf * X_F4;
    const float4* Wp = w4 + (size_t)s * KT4;
#pragma unroll
    for (int c4 = 0; c4 < KT4; ++c4) {
      float4 bv[4];
#pragma unroll
      for (int j = 0; j < 4; ++j)
        bv[j] = Wp[(size_t)j * (DIM / 4) + c4];
#pragma unroll
      for (int i = 0; i < 8; ++i) {
        int row = 8 * mg + i;
        float4 a = X[row * KT4 + (c4 ^ swz(row))];
#pragma unroll
        for (int j = 0; j < 4; ++j) {
          acc[i][j] = fmaf(a.x, bv[j].x, acc[i][j]);
          acc[i][j] = fmaf(a.y, bv[j].y, acc[i][j]);
          acc[i][j] = fmaf(a.z, bv[j].z, acc[i][j]);
          acc[i][j] = fmaf(a.w, bv[j].w, acc[i][j]);
        }
      }
    }
    __syncthreads();
    buf ^= 1;
  }

  // write partial logits [token][expert], float4 per thread-row
#pragma unroll
  for (int i = 0; i < 8; ++i) {
    int row = bm * MT + 8 * mg + i;
    float4 v = make_float4(acc[i][0], acc[i][1], acc[i][2], acc[i][3]);
    reinterpret_cast<float4*>(dst)[(size_t)row * (NE / 4) + ng] = v;
  }
}

// Combine: sum K-split partials, scale by 1/(|T|+eps), top-2, softmax, scatter.
// One wave per token; lane == expert. grid = TOKENS/4, block = 256.
__global__ __launch_bounds__(256)
void dr_combine(const float* __restrict__ p0, const float* __restrict__ pws,
                int nparts, const float* __restrict__ temp,
                float* __restrict__ outr, float* __restrict__ outi)
{
  int tok = blockIdx.x * 4 + (threadIdx.x >> 6);
  int e   = threadIdx.x & 63;
  float invT = 1.0f / (fabsf(temp[0]) + 1e-5f);
  size_t base = (size_t)tok * NE + e;

  float v = p0[base];
  for (int q = 1; q < nparts; ++q)
    v += pws[(size_t)(q - 1) * PART_ELEMS + base];
  v *= invT;

  // top-1 (ties -> lower index, matching lax.top_k)
  float bv = v; int bi = e;
#pragma unroll
  for (int off = 32; off; off >>= 1) {
    float ov = __shfl_xor(bv, off);
    int   oi = __shfl_xor(bi, off);
    if (ov > bv || (ov == bv && oi < bi)) { bv = ov; bi = oi; }
  }
  float v0 = bv; int i0 = bi;

  // top-2
  float vm = (e == i0) ? -INFINITY : v;
  bv = vm; bi = e;
#pragma unroll
  for (int off = 32; off; off >>= 1) {
    float ov = __shfl_xor(bv, off);
    int   oi = __shfl_xor(bi, off);
    if (ov > bv || (ov == bv && oi < bi)) { bv = ov; bi = oi; }
  }
  float v1 = bv; int i1 = bi;

  float ed = expf(v1 - v0);            // <= 1, already temperature-scaled
  float s  = 1.0f / (1.0f + ed);
  float w0 = s, w1 = ed * s;

  outr[base] = (e == i0) ? w0 : (e == i1) ? w1 : 0.0f;
  if (e == 0) {
    outi[(size_t)tok * 2]     = (float)i0;   // harness reads flat buffer as fp32
    outi[(size_t)tok * 2 + 1] = (float)i1;
  }
}

extern "C" void kernel_launch(void* const* d_in, const int* in_sizes, int n_in,
                              void* d_out, int out_size, void* d_ws, size_t ws_size,
                              hipStream_t stream)
{
  const float* x  = (const float*)d_in[0];
  const float* gw = (const float*)d_in[1];
  const float* tp = (const float*)d_in[2];
  float* outr = (float*)d_out;
  float* outi = outr + PART_ELEMS;

  const size_t part_bytes = PART_ELEMS * sizeof(float);
  int split = 1;
  if      (ws_size >= 7 * part_bytes) split = 8;
  else if (ws_size >= 3 * part_bytes) split = 4;
  else if (ws_size >= 1 * part_bytes) split = 2;
  const int steps = 128 / split;   // (DIM/KT) / split

  // part 0 -> routing region of d_out (scratch until combine), parts 1.. -> ws
  dr_gemm<<<dim3(128 * split), dim3(256), 0, stream>>>(x, gw, outr, (float*)d_ws, steps);
  dr_combine<<<dim3(TOKENS / 4), dim3(256), 0, stream>>>(outr, (const float*)d_ws,
                                                         split, tp, outr, outi);
}

// Round 3
// 636.371 us; speedup vs baseline: 1.0703x; 1.0703x over previous
//
#include <hip/hip_runtime.h>
#include <cstdint>
#include <cstddef>
#include <math.h>

#define TOKENS 16384
#define DIM    4096
#define NE     64
#define MT     128          // tokens per block tile
#define KT     32           // k elements staged per step
#define KT4    (KT/4)       // float4 per row = 8
#define X_F4   (MT*KT4)     // 1024 float4 per x buffer (16 KB)
#define W_F4   (NE*KT4)     // 512  float4 per w buffer (8 KB)
#define NSTEPS (DIM/KT)     // 128 total K-steps
#define PART_ELEMS ((size_t)TOKENS * NE)

static_assert(TOKENS % MT == 0, "tile");

__device__ __forceinline__ int swz(int row) { return (row >> 2) & 7; }

__device__ __forceinline__ void gload16(const void* g, void* l) {
  __builtin_amdgcn_global_load_lds(
      (const __attribute__((address_space(1))) void*)g,
      (__attribute__((address_space(3))) void*)l, 16, 0, 0);
}

// GEMM: partial logits [token][expert] for one K-split.
// grid = 128 m-tiles * split (split=6 -> 768 = exactly 3 blocks/CU), block = 256.
// X and W both LDS-staged (double-buffered, 48 KB -> 3 blocks/CU).
__global__ __launch_bounds__(256, 3)
void dr_gemm(const float* __restrict__ x, const float* __restrict__ gw,
             float* __restrict__ p0, float* __restrict__ pws,
             int steps_base, int steps_rem)
{
  __shared__ float4 xs4[2 * X_F4];
  __shared__ float4 ws4[2 * W_F4];

  const int t    = threadIdx.x;
  const int lane = t & 63;
  const int wv   = t >> 6;     // wave 0..3
  const int ng   = t & 15;     // expert-group thread (4 experts)
  const int mg   = t >> 4;     // token-group thread (8 tokens)

  const int bm    = blockIdx.x & 127;
  const int h     = blockIdx.x >> 7;            // K-split index
  const int steps = steps_base + (h < steps_rem ? 1 : 0);
  const int kbase = (h * steps_base + min(h, steps_rem)) * KT;
  float* __restrict__ dst = h ? (pws + (size_t)(h - 1) * PART_ELEMS) : p0;

  // --- staging constants: 32-bit byte offsets (x is 256 MB, w 1 MB) ---
  uint32_t xoff[4]; int xlds[4];
#pragma unroll
  for (int r = 0; r < 4; ++r) {
    int row = r * 32 + wv * 8 + (lane >> 3);          // 0..127
    int c4  = (lane & 7) ^ swz(row);                  // pre-swizzled source column
    xoff[r] = (uint32_t)(((bm * MT + row) * (size_t)DIM + kbase + 4 * c4) * sizeof(float));
    xlds[r] = (r * 32 + wv * 8) * KT4;                // wave-uniform LDS base (float4)
  }
  uint32_t woff[2]; int wlds[2];
#pragma unroll
  for (int r = 0; r < 2; ++r) {
    int row = r * 32 + wv * 8 + (lane >> 3);          // 0..63
    int c4  = (lane & 7) ^ swz(row);
    woff[r] = (uint32_t)((row * (size_t)DIM + kbase + 4 * c4) * sizeof(float));
    wlds[r] = (r * 32 + wv * 8) * KT4;
  }

  const char* xb = (const char*)x;
  const char* wb = (const char*)gw;

  auto stage = [&](int buf, int sidx) {
    uint32_t kb = (uint32_t)sidx * (KT * sizeof(float));
#pragma unroll
    for (int r = 0; r < 4; ++r)
      gload16(xb + (size_t)(xoff[r] + kb), (void*)(xs4 + buf * X_F4 + xlds[r]));
#pragma unroll
    for (int r = 0; r < 2; ++r)
      gload16(wb + (size_t)(woff[r] + kb), (void*)(ws4 + buf * W_F4 + wlds[r]));
  };

  float acc[8][4];
#pragma unroll
  for (int i = 0; i < 8; ++i)
#pragma unroll
    for (int j = 0; j < 4; ++j) acc[i][j] = 0.f;

  stage(0, 0);
  __syncthreads();

  int buf = 0;
#pragma unroll 1
  for (int s = 0; s < steps; ++s) {
    if (s + 1 < steps) stage(buf ^ 1, s + 1);   // async prefetch, drained at barrier
    const float4* X = xs4 + buf * X_F4;
    const float4* W = ws4 + buf * W_F4;
#pragma unroll
    for (int c4 = 0; c4 < KT4; ++c4) {
      float4 bv[4];
#pragma unroll
      for (int j = 0; j < 4; ++j) {
        int row = 4 * ng + j;
        bv[j] = W[row * KT4 + (c4 ^ swz(row))];
      }
#pragma unroll
      for (int i = 0; i < 8; ++i) {
        int row = 8 * mg + i;
        float4 a = X[row * KT4 + (c4 ^ swz(row))];
#pragma unroll
        for (int j = 0; j < 4; ++j) {
          acc[i][j] = fmaf(a.x, bv[j].x, acc[i][j]);
          acc[i][j] = fmaf(a.y, bv[j].y, acc[i][j]);
          acc[i][j] = fmaf(a.z, bv[j].z, acc[i][j]);
          acc[i][j] = fmaf(a.w, bv[j].w, acc[i][j]);
        }
      }
    }
    __syncthreads();
    buf ^= 1;
  }

  // write partial logits [token][expert], float4 per thread-row
#pragma unroll
  for (int i = 0; i < 8; ++i) {
    int row = bm * MT + 8 * mg + i;
    float4 v = make_float4(acc[i][0], acc[i][1], acc[i][2], acc[i][3]);
    reinterpret_cast<float4*>(dst)[(size_t)row * (NE / 4) + ng] = v;
  }
}

// Combine: sum K-split partials, scale by 1/(|T|+eps), top-2, softmax, scatter.
// One wave per token; lane == expert. grid = TOKENS/4, block = 256.
__global__ __launch_bounds__(256)
void dr_combine(const float* __restrict__ p0, const float* __restrict__ pws,
                int nparts, const float* __restrict__ temp,
                float* __restrict__ outr, float* __restrict__ outi)
{
  int tok = blockIdx.x * 4 + (threadIdx.x >> 6);
  int e   = threadIdx.x & 63;
  float invT = 1.0f / (fabsf(temp[0]) + 1e-5f);
  size_t base = (size_t)tok * NE + e;

  float v = p0[base];
  for (int q = 1; q < nparts; ++q)
    v += pws[(size_t)(q - 1) * PART_ELEMS + base];
  v *= invT;

  // top-1 (ties -> lower index, matching lax.top_k)
  float bv = v; int bi = e;
#pragma unroll
  for (int off = 32; off; off >>= 1) {
    float ov = __shfl_xor(bv, off);
    int   oi = __shfl_xor(bi, off);
    if (ov > bv || (ov == bv && oi < bi)) { bv = ov; bi = oi; }
  }
  float v0 = bv; int i0 = bi;

  // top-2
  float vm = (e == i0) ? -INFINITY : v;
  bv = vm; bi = e;
#pragma unroll
  for (int off = 32; off; off >>= 1) {
    float ov = __shfl_xor(bv, off);
    int   oi = __shfl_xor(bi, off);
    if (ov > bv || (ov == bv && oi < bi)) { bv = ov; bi = oi; }
  }
  float v1 = bv; int i1 = bi;

  float ed = expf(v1 - v0);            // <= 1, already temperature-scaled
  float s  = 1.0f / (1.0f + ed);
  float w0 = s, w1 = ed * s;

  outr[base] = (e == i0) ? w0 : (e == i1) ? w1 : 0.0f;
  if (e == 0) {
    outi[(size_t)tok * 2]     = (float)i0;   // harness reads flat buffer as fp32
    outi[(size_t)tok * 2 + 1] = (float)i1;
  }
}

extern "C" void kernel_launch(void* const* d_in, const int* in_sizes, int n_in,
                              void* d_out, int out_size, void* d_ws, size_t ws_size,
                              hipStream_t stream)
{
  const float* x  = (const float*)d_in[0];
  const float* gw = (const float*)d_in[1];
  const float* tp = (const float*)d_in[2];
  float* outr = (float*)d_out;
  float* outi = outr + PART_ELEMS;

  const size_t part_bytes = PART_ELEMS * sizeof(float);
  // split=6 -> grid 768 = exactly 3 blocks/CU (no tail); fall back if ws small
  int split = 1;
  if      (ws_size >= 5 * part_bytes) split = 6;
  else if (ws_size >= 3 * part_bytes) split = 4;
  else if (ws_size >= 1 * part_bytes) split = 2;

  const int steps_base = NSTEPS / split;
  const int steps_rem  = NSTEPS % split;

  // part 0 -> routing region of d_out (scratch until combine), parts 1.. -> ws
  dr_gemm<<<dim3(128 * split), dim3(256), 0, stream>>>(x, gw, outr, (float*)d_ws,
                                                       steps_base, steps_rem);
  dr_combine<<<dim3(TOKENS / 4), dim3(256), 0, stream>>>(outr, (const float*)d_ws,
                                                         split, tp, outr, outi);
}

// Round 5
// 464.818 us; speedup vs baseline: 1.4653x; 1.3691x over previous
//
#include <hip/hip_runtime.h>
#include <cstdint>
#include <cstddef>
#include <math.h>

#define TOKENS 16384
#define DIM    4096
#define NE     64
#define MT     256          // tokens per block tile
#define KT     16           // k elements per pipeline step
#define KT4    (KT/4)       // 4 float4 per row
#define NBUF   4            // 4-deep buffer ring, prefetch distance 2
#define XF4    (MT*KT4)     // 1024 float4 = 16 KB per X buffer
#define WF4    (NE*KT4)     // 256 float4  = 4 KB per W buffer
#define PART_ELEMS ((size_t)TOKENS * NE)

// involutive per-row column swizzle (2 bits, covers c4 0..3): keeps every
// wave-read <=2-way bank aliased (free, m136). Applied on stage SOURCE and
// on READ (both-sides-or-neither, rule #21).
__device__ __forceinline__ int swz2(int row) { return ((row >> 2) ^ (row >> 4)) & 3; }

__device__ __forceinline__ void gload16(const void* g, void* l) {
  __builtin_amdgcn_global_load_lds(
      (const __attribute__((address_space(1))) void*)g,
      (__attribute__((address_space(3))) void*)l, 16, 0, 0);
}

// Partial-logits GEMM, one K-split per block. grid = 64 m-tiles * split.
// 4-buffer ring, prefetch distance 2, ONE raw s_barrier + vmcnt(10) per step
// (never drains to 0 in the loop). 80 KB LDS -> 2 blocks/CU, 8 waves/CU.
__global__ __launch_bounds__(256, 2)
void dr_gemm(const float* __restrict__ x, const float* __restrict__ gw,
             float* __restrict__ p0, float* __restrict__ pws, int steps)
{
  __shared__ float4 xs [NBUF * XF4];   // 64 KB
  __shared__ float4 wsh[NBUF * WF4];   // 16 KB

  const int t = threadIdx.x, lane = t & 63, wv = t >> 6;
  const int ng = t & 7;        // expert group: experts 8*ng..8*ng+7
  const int mg = t >> 3;       // token group:  rows 8*mg..8*mg+7
  const int bm = blockIdx.x & 63;
  const int h  = blockIdx.x >> 6;            // K-split index
  const int kbase = h * steps * KT;
  float* __restrict__ dst = h ? pws + (size_t)(h - 1) * PART_ELEMS : p0;

  // --- staging constants (dest = wave-uniform base + lane*16B, source pre-swizzled)
  uint32_t xoff[4]; uint32_t xldsb[4];
#pragma unroll
  for (int r = 0; r < 4; ++r) {
    int row = r * 64 + wv * 16 + (lane >> 2);                 // 0..255
    int c4s = (lane & 3) ^ swz2(row);
    xoff[r]  = (uint32_t)(((size_t)(bm * MT + row) * DIM + kbase + 4 * c4s) * 4);
    xldsb[r] = (uint32_t)((r * 64 + wv * 16) * KT4);          // float4 idx
  }
  const int wrow = wv * 16 + (lane >> 2);                     // 0..63
  const uint32_t woff  = (uint32_t)(((size_t)wrow * DIM + kbase +
                                     4 * ((lane & 3) ^ swz2(wrow))) * 4);
  const uint32_t wldsb = (uint32_t)((wv * 16) * KT4);

  const char* xb = (const char*)x;
  const char* wb = (const char*)gw;

  auto stage = [&](int buf, int sidx) {
    uint32_t kb = (uint32_t)sidx * (KT * 4);
#pragma unroll
    for (int r = 0; r < 4; ++r)
      gload16(xb + (size_t)(xoff[r] + kb), (void*)(xs + buf * XF4 + xldsb[r]));
    gload16(wb + (size_t)(woff + kb), (void*)(wsh + buf * WF4 + wldsb));
  };

  // --- per-thread read constants (static-indexed arrays stay in VGPRs)
  int xbase[8], xsw[8], wbase[8], wsw[8];
#pragma unroll
  for (int i = 0; i < 8; ++i) { int row = 8 * mg + i; xbase[i] = row * KT4; xsw[i] = swz2(row); }
#pragma unroll
  for (int j = 0; j < 8; ++j) { int row = 8 * ng + j; wbase[j] = row * KT4; wsw[j] = swz2(row); }

  float acc[8][8];
#pragma unroll
  for (int i = 0; i < 8; ++i)
#pragma unroll
    for (int j = 0; j < 8; ++j) acc[i][j] = 0.f;

  stage(0, 0);
  stage(1, 1);

#pragma unroll 1
  for (int s = 0; s < steps; ++s) {
    // prefetch distance 2; tail wraps into DEAD buffers (uniform vmcnt literal)
    int s2 = s + 2; if (s2 >= steps) s2 -= steps;
    stage((s + 2) & 3, s2);
    // wait until only the 2 newest stages (2*5 loads) are outstanding ->
    // stage(s) has landed; barrier makes all waves' stage(s) visible.
    asm volatile("s_waitcnt vmcnt(10)" ::: "memory");
    __builtin_amdgcn_s_barrier();
    __builtin_amdgcn_sched_barrier(0);

    const float4* X = xs  + (s & 3) * XF4;
    const float4* W = wsh + (s & 3) * WF4;
#pragma unroll
    for (int c4 = 0; c4 < KT4; ++c4) {
      float4 wv4[8];
#pragma unroll
      for (int j = 0; j < 8; ++j) wv4[j] = W[wbase[j] + (c4 ^ wsw[j])];
#pragma unroll
      for (int i = 0; i < 8; ++i) {
        float4 a = X[xbase[i] + (c4 ^ xsw[i])];
#pragma unroll
        for (int j = 0; j < 8; ++j) {
          acc[i][j] = fmaf(a.x, wv4[j].x, acc[i][j]);
          acc[i][j] = fmaf(a.y, wv4[j].y, acc[i][j]);
          acc[i][j] = fmaf(a.z, wv4[j].z, acc[i][j]);
          acc[i][j] = fmaf(a.w, wv4[j].w, acc[i][j]);
        }
      }
    }
    // no trailing barrier needed: writer of buf b at step s targets a buffer
    // last read at step s-2, sealed by the barrier at step s-1.
  }

  // epilogue: thread owns tokens 8*mg..+7, experts 8*ng..+7 (two float4 runs)
#pragma unroll
  for (int i = 0; i < 8; ++i) {
    int row = bm * MT + 8 * mg + i;
    float4 v0 = make_float4(acc[i][0], acc[i][1], acc[i][2], acc[i][3]);
    float4 v1 = make_float4(acc[i][4], acc[i][5], acc[i][6], acc[i][7]);
    float4* d = reinterpret_cast<float4*>(dst) + (size_t)row * (NE / 4) + 2 * ng;
    d[0] = v0; d[1] = v1;
  }
}

// Combine: sum K-split partials, scale by 1/(|T|+eps), top-2, softmax, scatter.
// One wave per token; lane == expert. grid = TOKENS/4, block = 256.
__global__ __launch_bounds__(256)
void dr_combine(const float* __restrict__ p0, const float* __restrict__ pws,
                int nparts, const float* __restrict__ temp,
                float* __restrict__ outr, float* __restrict__ outi)
{
  int tok = blockIdx.x * 4 + (threadIdx.x >> 6);
  int e   = threadIdx.x & 63;
  float invT = 1.0f / (fabsf(temp[0]) + 1e-5f);
  size_t base = (size_t)tok * NE + e;

  float v = p0[base];
  for (int q = 1; q < nparts; ++q)
    v += pws[(size_t)(q - 1) * PART_ELEMS + base];
  v *= invT;

  // top-1 (ties -> lower index, matching lax.top_k)
  float bv = v; int bi = e;
#pragma unroll
  for (int off = 32; off; off >>= 1) {
    float ov = __shfl_xor(bv, off);
    int   oi = __shfl_xor(bi, off);
    if (ov > bv || (ov == bv && oi < bi)) { bv = ov; bi = oi; }
  }
  float v0 = bv; int i0 = bi;

  // top-2
  float vm = (e == i0) ? -INFINITY : v;
  bv = vm; bi = e;
#pragma unroll
  for (int off = 32; off; off >>= 1) {
    float ov = __shfl_xor(bv, off);
    int   oi = __shfl_xor(bi, off);
    if (ov > bv || (ov == bv && oi < bi)) { bv = ov; bi = oi; }
  }
  float v1 = bv; int i1 = bi;

  float ed = expf(v1 - v0);            // <= 1, already temperature-scaled
  float s  = 1.0f / (1.0f + ed);
  float w0 = s, w1 = ed * s;

  outr[base] = (e == i0) ? w0 : (e == i1) ? w1 : 0.0f;
  if (e == 0) {
    outi[(size_t)tok * 2]     = (float)i0;   // harness reads flat buffer as fp32
    outi[(size_t)tok * 2 + 1] = (float)i1;
  }
}

extern "C" void kernel_launch(void* const* d_in, const int* in_sizes, int n_in,
                              void* d_out, int out_size, void* d_ws, size_t ws_size,
                              hipStream_t stream)
{
  const float* x  = (const float*)d_in[0];
  const float* gw = (const float*)d_in[1];
  const float* tp = (const float*)d_in[2];
  float* outr = (float*)d_out;
  float* outi = outr + PART_ELEMS;

  const size_t part_bytes = PART_ELEMS * sizeof(float);
  // split=8 -> grid 512 = exactly 2 blocks/CU (80 KB LDS), tail-free
  int split = 2;
  if      (ws_size >= 7 * part_bytes) split = 8;
  else if (ws_size >= 3 * part_bytes) split = 4;
  const int steps = (DIM / KT) / split;

  // part 0 -> routing region of d_out (scratch until combine), parts 1.. -> ws
  dr_gemm<<<dim3(64 * split), dim3(256), 0, stream>>>(x, gw, outr, (float*)d_ws, steps);
  dr_combine<<<dim3(TOKENS / 4), dim3(256), 0, stream>>>(outr, (const float*)d_ws,
                                                         split, tp, outr, outi);
}

// Round 6
// 425.080 us; speedup vs baseline: 1.6023x; 1.0935x over previous
//
#include <hip/hip_runtime.h>
#include <cstdint>
#include <cstddef>
#include <math.h>

#define TOKENS 16384
#define DIM    4096
#define NE     64
#define MB     128                 // tokens per block
#define KSTEP  16                  // k per pipeline step (one MFMA-K)
#define NKS    (DIM/KSTEP)         // 256 global k-steps
#define PART_ELEMS ((size_t)TOKENS * NE)
#define WFRAG_BYTES ((size_t)NKS * 6 * 1024)   // 1.5 MB frag-ordered W
#define PART_OFF    ((size_t)2 * 1024 * 1024)

typedef short bf16x8 __attribute__((ext_vector_type(8)));   // 8 bf16 (4 VGPR)
typedef float f32x16 __attribute__((ext_vector_type(16)));  // 32x32 acc

static __device__ __forceinline__ float bmask(float x) {    // bf16-truncate (exact prefix)
  return __uint_as_float(__float_as_uint(x) & 0xffff0000u);
}
static __device__ __forceinline__ short btrunc(float x) {
  return (short)(__float_as_uint(x) >> 16);
}
__device__ __forceinline__ void gload16(const void* g, void* l) {
  __builtin_amdgcn_global_load_lds(
      (const __attribute__((address_space(1))) void*)g,
      (__attribute__((address_space(3))) void*)l, 16, 0, 0);
}

// ---- prep: W fp32 -> frag-ordered bf16 {hi,mid,lo}. x = hi+mid+lo EXACTLY.
// layout: wfrag[(ks*6 + nt*3 + lv)*1024 + lane*16] = 8 bf16 for B-frag slot:
//   B[k=(l>>5)*8+j][col=l&31] = W[nt*32+(l&31)][ks*16+(l>>5)*8+j]
__global__ __launch_bounds__(384)
void dr_prep(const float* __restrict__ gw, char* __restrict__ wfrag)
{
  const int ks = blockIdx.x;              // 0..255
  const int f  = threadIdx.x >> 6;        // 0..5 = nt*3+lv
  const int l  = threadIdx.x & 63;
  const int nt = f / 3, lv = f - 3 * nt;
  const int e  = nt * 32 + (l & 31);
  const int k0 = ks * 16 + (l >> 5) * 8;
  const float* src = gw + (size_t)e * DIM + k0;
  float4 a = *(const float4*)(src);
  float4 b = *(const float4*)(src + 4);
  float v[8] = {a.x, a.y, a.z, a.w, b.x, b.y, b.z, b.w};
  bf16x8 o;
#pragma unroll
  for (int j = 0; j < 8; ++j) {
    float x  = v[j];
    float hi = bmask(x);
    float r1 = x - hi;            // exact
    float mi = bmask(r1);
    float lo = bmask(r1 - mi);    // exact residue, <=8 sig bits
    o[j] = btrunc(lv == 0 ? hi : (lv == 1 ? mi : lo));
  }
  *(bf16x8*)(wfrag + ((size_t)ks * 6 + f) * 1024 + l * 16) = o;
}

// ---- GEMM: logits[m][e] partials via 6 bf16 MFMA products per k-step.
// block = 256 thr (4 waves), M-block 128 (wave w: rows w*32..+32, all 64 experts),
// grid = 128 m-tiles * split. LDS 36KB -> 2 blocks/CU.
__global__ __launch_bounds__(256, 2)
void dr_gemm(const float* __restrict__ x, const char* __restrict__ wfrag,
             float* __restrict__ p0, float* __restrict__ pws, int steps)
{
  __shared__ char lds[36864];   // A: 2buf*3lv*4msub KB @0 ; W: 2buf*6frag KB @24576
  const int t = threadIdx.x, l = t & 63, w = t >> 6;
  const int bm = blockIdx.x & 127, h = blockIdx.x >> 7;
  const int ks0 = h * steps;
  float* __restrict__ dst = h ? pws + (size_t)(h - 1) * PART_ELEMS : p0;

  // X staging: thread stages row (w*32 + l&31), k-chunk (l>>5)*8 — exactly its
  // wave's A-frag slot. Pairs of half-waves cover full 64B per row (coalesced).
  const int arow = bm * MB + w * 32 + (l & 31);
  const float* xsrc = x + (size_t)arow * DIM + (l >> 5) * 8;

  f32x16 acc0 = {0,0,0,0,0,0,0,0,0,0,0,0,0,0,0,0};
  f32x16 acc1 = {0,0,0,0,0,0,0,0,0,0,0,0,0,0,0,0};

  auto stageW = [&](int sb, int sg) {           // W frags: global_load_lds, linear
    if (w == (sg & 3)) {                         // rotate issuing wave
#pragma unroll
      for (int f = 0; f < 6; ++f)
        gload16(wfrag + ((size_t)sg * 6 + f) * 1024 + l * 16,
                (void*)(lds + 24576 + (sb * 6 + f) * 1024));
    }
  };
  auto cvtWrite = [&](int nb, float4 x0, float4 x1) {   // split + frag-order write
    float v[8] = {x0.x, x0.y, x0.z, x0.w, x1.x, x1.y, x1.z, x1.w};
    bf16x8 h8, m8, l8;
#pragma unroll
    for (int j = 0; j < 8; ++j) {
      float xx = v[j];
      float hi = bmask(xx);
      float r1 = xx - hi;
      float mi = bmask(r1);
      float lo = bmask(r1 - mi);
      h8[j] = btrunc(hi); m8[j] = btrunc(mi); l8[j] = btrunc(lo);
    }
    char* base = lds + (size_t)w * 1024 + l * 16;
    *(bf16x8*)(base + (nb * 3 + 0) * 4096) = h8;
    *(bf16x8*)(base + (nb * 3 + 1) * 4096) = m8;
    *(bf16x8*)(base + (nb * 3 + 2) * 4096) = l8;
  };

  // prologue: stage k-step ks0 into buf 0
  float4 xr0 = *(const float4*)(xsrc + (size_t)ks0 * KSTEP);
  float4 xr1 = *(const float4*)(xsrc + (size_t)ks0 * KSTEP + 4);
  stageW(0, ks0);
  cvtWrite(0, xr0, xr1);
  __syncthreads();

#pragma unroll 1
  for (int s = 0; s < steps; ++s) {
    const int cb = s & 1, nb = cb ^ 1;
    const bool more = (s + 1) < steps;
    if (more) {
      xr0 = *(const float4*)(xsrc + (size_t)(ks0 + s + 1) * KSTEP);
      xr1 = *(const float4*)(xsrc + (size_t)(ks0 + s + 1) * KSTEP + 4);
      stageW(nb, ks0 + s + 1);
    }
    // fragment reads: fully contiguous per wave (frag order) — conflict-free
    const char* abase = lds + (size_t)w * 1024 + l * 16;
    bf16x8 Ah = *(const bf16x8*)(abase + (cb * 3 + 0) * 4096);
    bf16x8 Am = *(const bf16x8*)(abase + (cb * 3 + 1) * 4096);
    bf16x8 Al = *(const bf16x8*)(abase + (cb * 3 + 2) * 4096);
    const char* bbase = lds + 24576 + (size_t)cb * 6144 + l * 16;
    bf16x8 B0h = *(const bf16x8*)(bbase + 0 * 1024);
    bf16x8 B0m = *(const bf16x8*)(bbase + 1 * 1024);
    bf16x8 B0l = *(const bf16x8*)(bbase + 2 * 1024);
    bf16x8 B1h = *(const bf16x8*)(bbase + 3 * 1024);
    bf16x8 B1m = *(const bf16x8*)(bbase + 4 * 1024);
    bf16x8 B1l = *(const bf16x8*)(bbase + 5 * 1024);

    acc0 = __builtin_amdgcn_mfma_f32_32x32x16_bf16(Ah, B0h, acc0, 0, 0, 0);
    acc1 = __builtin_amdgcn_mfma_f32_32x32x16_bf16(Ah, B1h, acc1, 0, 0, 0);
    acc0 = __builtin_amdgcn_mfma_f32_32x32x16_bf16(Ah, B0m, acc0, 0, 0, 0);
    acc1 = __builtin_amdgcn_mfma_f32_32x32x16_bf16(Ah, B1m, acc1, 0, 0, 0);
    acc0 = __builtin_amdgcn_mfma_f32_32x32x16_bf16(Am, B0h, acc0, 0, 0, 0);
    acc1 = __builtin_amdgcn_mfma_f32_32x32x16_bf16(Am, B1h, acc1, 0, 0, 0);
    acc0 = __builtin_amdgcn_mfma_f32_32x32x16_bf16(Ah, B0l, acc0, 0, 0, 0);
    acc1 = __builtin_amdgcn_mfma_f32_32x32x16_bf16(Ah, B1l, acc1, 0, 0, 0);
    acc0 = __builtin_amdgcn_mfma_f32_32x32x16_bf16(Am, B0m, acc0, 0, 0, 0);
    acc1 = __builtin_amdgcn_mfma_f32_32x32x16_bf16(Am, B1m, acc1, 0, 0, 0);
    acc0 = __builtin_amdgcn_mfma_f32_32x32x16_bf16(Al, B0h, acc0, 0, 0, 0);
    acc1 = __builtin_amdgcn_mfma_f32_32x32x16_bf16(Al, B1h, acc1, 0, 0, 0);

    if (more) cvtWrite(nb, xr0, xr1);
    __syncthreads();   // drains vmcnt (W gload_lds) + lgkm (A writes)
  }

  // epilogue: C/D layout (m74): col = lane&31, row = (q&3) + 8*(q>>2) + 4*(lane>>5)
#pragma unroll
  for (int q = 0; q < 16; ++q) {
    int row = (q & 3) + 8 * (q >> 2) + 4 * (l >> 5);
    size_t gr = (size_t)(bm * MB + w * 32 + row) * NE;
    dst[gr + (l & 31)]      = acc0[q];
    dst[gr + 32 + (l & 31)] = acc1[q];
  }
}

// ---- Combine: sum split partials, scale, top-2, softmax, scatter.
__global__ __launch_bounds__(256)
void dr_combine(const float* __restrict__ p0, const float* __restrict__ pws,
                int nparts, const float* __restrict__ temp,
                float* __restrict__ outr, float* __restrict__ outi)
{
  int tok = blockIdx.x * 4 + (threadIdx.x >> 6);
  int e   = threadIdx.x & 63;
  float invT = 1.0f / (fabsf(temp[0]) + 1e-5f);
  size_t base = (size_t)tok * NE + e;

  float v = p0[base];
  for (int q = 1; q < nparts; ++q)
    v += pws[(size_t)(q - 1) * PART_ELEMS + base];
  v *= invT;

  float bv = v; int bi = e;
#pragma unroll
  for (int off = 32; off; off >>= 1) {
    float ov = __shfl_xor(bv, off);
    int   oi = __shfl_xor(bi, off);
    if (ov > bv || (ov == bv && oi < bi)) { bv = ov; bi = oi; }
  }
  float v0 = bv; int i0 = bi;

  float vm = (e == i0) ? -INFINITY : v;
  bv = vm; bi = e;
#pragma unroll
  for (int off = 32; off; off >>= 1) {
    float ov = __shfl_xor(bv, off);
    int   oi = __shfl_xor(bi, off);
    if (ov > bv || (ov == bv && oi < bi)) { bv = ov; bi = oi; }
  }
  float v1 = bv; int i1 = bi;

  float ed = expf(v1 - v0);
  float s  = 1.0f / (1.0f + ed);
  float w0 = s, w1 = ed * s;

  outr[base] = (e == i0) ? w0 : (e == i1) ? w1 : 0.0f;
  if (e == 0) {
    outi[(size_t)tok * 2]     = (float)i0;
    outi[(size_t)tok * 2 + 1] = (float)i1;
  }
}

extern "C" void kernel_launch(void* const* d_in, const int* in_sizes, int n_in,
                              void* d_out, int out_size, void* d_ws, size_t ws_size,
                              hipStream_t stream)
{
  const float* x  = (const float*)d_in[0];
  const float* gw = (const float*)d_in[1];
  const float* tp = (const float*)d_in[2];
  float* outr = (float*)d_out;
  float* outi = outr + PART_ELEMS;
  char*  wfrag = (char*)d_ws;
  float* parts = (float*)((char*)d_ws + PART_OFF);

  const size_t part_bytes = PART_ELEMS * sizeof(float);
  int split = 1;
  if      (ws_size >= PART_OFF + 3 * part_bytes) split = 4;   // grid 512 = 2 blk/CU
  else if (ws_size >= PART_OFF + 1 * part_bytes) split = 2;
  const int steps = NKS / split;

  dr_prep<<<dim3(NKS), dim3(384), 0, stream>>>(gw, wfrag);
  dr_gemm<<<dim3(128 * split), dim3(256), 0, stream>>>(x, wfrag, outr, parts, steps);
  dr_combine<<<dim3(TOKENS / 4), dim3(256), 0, stream>>>(outr, parts, split, tp,
                                                         outr, outi);
}